// Round 16
// baseline (154.453 us; speedup 1.0000x reference)
//
#include <hip/hip_runtime.h>
#include <math.h>

#define N_NODES 50000
#define E_EDGES 800000
#define D_FEAT  64
#define C_CH    3
#define H_HID   8
#define OUT_F   128
#define CD      192              // C*D
#define NTILES  (N_NODES / 16)   // 3125 exact
#define NBLK_SCAN ((N_NODES + 255) / 256)   // 196
#define PLACE_CHUNK  2048
#define PLACE_SLICES ((E_EDGES + PLACE_CHUNK - 1) / PLACE_CHUNK)  // 391
#define NPART8 (N_NODES / 8)     // 6250 exact
#define XCVT_BLOCKS (N_NODES * D_FEAT / 4 / 256)   // 3125
#define HIST_BLOCKS (E_EDGES / 256)                // 3125

typedef _Float16 half8 __attribute__((ext_vector_type(8)));
typedef _Float16 half4 __attribute__((ext_vector_type(4)));
typedef float    f32x4 __attribute__((ext_vector_type(4)));
typedef int      i32x4 __attribute__((ext_vector_type(4)));
typedef unsigned u32x2 __attribute__((ext_vector_type(2)));

__device__ __forceinline__ float lrelu(float v) { return v >= 0.f ? v : 0.01f * v; }

__device__ __forceinline__ unsigned short f2h_bits(float f) {
    _Float16 h = (_Float16)f;
    unsigned short b;
    __builtin_memcpy(&b, &h, 2);
    return b;
}
__device__ __forceinline__ float h2f_bits(unsigned b) {
    unsigned short s = (unsigned short)b;
    _Float16 h;
    __builtin_memcpy(&h, &s, 2);
    return (float)h;
}

// --- K1: fused {x f32->f16 convert} + {dst histogram} -----------------------
// All accesses are stream-once -> non-temporal (keep L2 clean).
__global__ __launch_bounds__(256) void k_pre(
    const float* __restrict__ x, _Float16* __restrict__ xh,
    const int* __restrict__ ei, int* __restrict__ counts)
{
    if (blockIdx.x < XCVT_BLOCKS) {
        int i = blockIdx.x * 256 + threadIdx.x;
        f32x4 f = __builtin_nontemporal_load((const f32x4*)x + i);
        half4 h;
        h[0] = (_Float16)f[0]; h[1] = (_Float16)f[1];
        h[2] = (_Float16)f[2]; h[3] = (_Float16)f[3];
        __builtin_nontemporal_store(h, (half4*)(xh + (size_t)i * 4));
        return;
    }
    int e = (blockIdx.x - XCVT_BLOCKS) * 256 + threadIdx.x;
    int d = __builtin_nontemporal_load(ei + E_EDGES + e);
    atomicAdd(counts + d, 1);   // no return use
}

// --- K2a: per-block sums of counts ------------------------------------------
__global__ __launch_bounds__(256) void k_blocksum(
    const int* __restrict__ counts, int* __restrict__ blocksums)
{
    __shared__ int s[256];
    int i = blockIdx.x * 256 + threadIdx.x;
    s[threadIdx.x] = (i < N_NODES) ? counts[i] : 0;
    __syncthreads();
    for (int off = 128; off >= 1; off >>= 1) {
        if (threadIdx.x < off) s[threadIdx.x] += s[threadIdx.x + off];
        __syncthreads();
    }
    if (threadIdx.x == 0) blocksums[blockIdx.x] = s[0];
}

// --- K2b: fused {scan of blocksums (redundant per block)} + final scan ------
__global__ __launch_bounds__(256) void k_scanfinal(
    const int* __restrict__ counts, const int* __restrict__ blocksums,
    int* __restrict__ offsets)
{
    __shared__ int bs[256];
    __shared__ int s[256];
    const int tid = threadIdx.x;

    bs[tid] = (tid < NBLK_SCAN) ? blocksums[tid] : 0;
    __syncthreads();
    for (int off = 1; off < 256; off <<= 1) {
        int t = (tid >= off) ? bs[tid - off] : 0;
        __syncthreads();
        bs[tid] += t;
        __syncthreads();
    }
    const int blockoff = (blockIdx.x == 0) ? 0 : bs[blockIdx.x - 1];

    int i = blockIdx.x * 256 + tid;
    int v = (i < N_NODES) ? counts[i] : 0;
    s[tid] = v;
    __syncthreads();
    for (int off = 1; off < 256; off <<= 1) {
        int t = (tid >= off) ? s[tid - off] : 0;
        __syncthreads();
        s[tid] += t;
        __syncthreads();
    }
    if (i < N_NODES) offsets[i] = s[tid] - v + blockoff;   // exclusive
}

// --- K3: XCD-partitioned edge-MLP + record scatter, COMPACTED ---------------
// group g = blockIdx&7 owns dst range [g*6250,(g+1)*6250). Streaming reads of
// ei/ea are NON-TEMPORAL so the XCD's L2 is reserved for write-combining the
// 'sorted' scatter lines (its 800KB region fits one L2). Scatter stores stay
// cached. Phase A ballot-compacts; phase B runs the MLP lane-dense.
__global__ __launch_bounds__(256) void k_place(
    const int* __restrict__ ei, const float* __restrict__ ea,
    const float* __restrict__ w1, const float* __restrict__ b1,
    const float* __restrict__ w2, const float* __restrict__ b2,
    int* __restrict__ offsets, uint2* __restrict__ sorted)
{
    __shared__ int   s_src[PLACE_CHUNK];
    __shared__ float s_ea [PLACE_CHUNK];
    __shared__ int   s_dd [PLACE_CHUNK];
    __shared__ int   lcnt;

    const int tid   = threadIdx.x;
    const int lane  = tid & 63;
    const int g     = blockIdx.x & 7;
    const int slice = blockIdx.x >> 3;
    const int lo    = g * NPART8;
    const int hi    = lo + NPART8;
    const int e0    = slice * PLACE_CHUNK + tid * 8;
    const int* dstp = ei + E_EDGES;

    if (tid == 0) lcnt = 0;
    __syncthreads();

    int   se[8];
    int   de[8];
    float aev[8];
    if (e0 + 7 < E_EDGES) {
        i32x4 sv0 = __builtin_nontemporal_load((const i32x4*)(ei + e0));
        i32x4 sv1 = __builtin_nontemporal_load((const i32x4*)(ei + e0 + 4));
        i32x4 d0  = __builtin_nontemporal_load((const i32x4*)(dstp + e0));
        i32x4 d1  = __builtin_nontemporal_load((const i32x4*)(dstp + e0 + 4));
        f32x4 a0  = __builtin_nontemporal_load((const f32x4*)(ea + e0));
        f32x4 a1  = __builtin_nontemporal_load((const f32x4*)(ea + e0 + 4));
        se[0]=sv0[0]; se[1]=sv0[1]; se[2]=sv0[2]; se[3]=sv0[3];
        se[4]=sv1[0]; se[5]=sv1[1]; se[6]=sv1[2]; se[7]=sv1[3];
        de[0]=d0[0];  de[1]=d0[1];  de[2]=d0[2];  de[3]=d0[3];
        de[4]=d1[0];  de[5]=d1[1];  de[6]=d1[2];  de[7]=d1[3];
        aev[0]=a0[0]; aev[1]=a0[1]; aev[2]=a0[2]; aev[3]=a0[3];
        aev[4]=a1[0]; aev[5]=a1[1]; aev[6]=a1[2]; aev[7]=a1[3];
    } else {
#pragma unroll
        for (int j = 0; j < 8; ++j) {
            int e = e0 + j;
            se[j]  = (e < E_EDGES) ? ei[e]   : 0;
            de[j]  = (e < E_EDGES) ? dstp[e] : -1;
            aev[j] = (e < E_EDGES) ? ea[e]   : 0.f;
        }
    }

    // phase A: wave-ballot compaction into LDS
#pragma unroll
    for (int j = 0; j < 8; ++j) {
        bool p = (de[j] >= lo && de[j] < hi);
        unsigned long long mask = __ballot(p);
        int total = __popcll(mask);
        int wbase = 0;
        if (lane == 0 && total) wbase = atomicAdd(&lcnt, total);
        wbase = __shfl(wbase, 0);
        if (p) {
            int pos = wbase + __popcll(mask & ((1ull << lane) - 1ull));
            s_src[pos] = se[j];
            s_ea [pos] = aev[j];
            s_dd [pos] = de[j];
        }
    }
    __syncthreads();

    // phase B: dense edge MLP + scatter (cached stores -> L2 write-combining)
    const int cnt = lcnt;
    for (int i = tid; i < cnt; i += 256) {
        float a = s_ea[i];
        float wc[C_CH];
#pragma unroll
        for (int c = 0; c < C_CH; ++c) {
            float s = 0.f;
#pragma unroll
            for (int h = 0; h < H_HID; ++h) {
                float t = fmaf(a, w1[c * H_HID + h], b1[c * H_HID + h]);
                t = (t >= 0.f) ? t : 0.01f * t;               // leaky_relu
                s = fmaf(t, w2[c * H_HID + h], s);
            }
            s += b2[c];
            wc[c] = (s > 0.f) ? s : expm1f(s);                // elu
        }
        uint2 r;
        r.x = (unsigned)s_src[i] | ((unsigned)f2h_bits(wc[0]) << 16);
        r.y = (unsigned)f2h_bits(wc[1]) | ((unsigned)f2h_bits(wc[2]) << 16);
        sorted[atomicAdd(offsets + s_dd[i], 1)] = r;
    }
}

// --- K4: gather (f16 x rows) + residual -> v[N][192] f16 --------------------
// Stream-once traffic (sorted reads, x residual reads, v writes) is
// non-temporal so L2 keeps the reused xh working set.
__global__ __launch_bounds__(256) void k_gather(
    const uint2* __restrict__ sorted, const int* __restrict__ endoff,
    const _Float16* __restrict__ xh, const float* __restrict__ x,
    const float* __restrict__ eps, _Float16* __restrict__ v)
{
    const int n    = blockIdx.x * 4 + (threadIdx.x >> 6);   // grid = N/4 exact
    const int lane = threadIdx.x & 63;

    const int start = (n == 0) ? 0 : endoff[n - 1];
    const int end   = endoff[n];

    float a0 = 0.f, a1 = 0.f, a2 = 0.f;
    float b0 = 0.f, b1 = 0.f, b2 = 0.f;
    float c0 = 0.f, c1 = 0.f, c2 = 0.f;
    float d0 = 0.f, d1 = 0.f, d2 = 0.f;

    for (int base = start; base < end; base += 64) {
        const int m = min(64, end - base);
        u32x2 rec = {0u, 0u};
        if (lane < m)
            rec = __builtin_nontemporal_load((const u32x2*)(sorted + base + lane));
        int j = 0;
        for (; j + 4 <= m; j += 4) {
            unsigned rxA = (unsigned)__shfl((int)rec[0], j);
            unsigned ryA = (unsigned)__shfl((int)rec[1], j);
            unsigned rxB = (unsigned)__shfl((int)rec[0], j + 1);
            unsigned ryB = (unsigned)__shfl((int)rec[1], j + 1);
            unsigned rxC = (unsigned)__shfl((int)rec[0], j + 2);
            unsigned ryC = (unsigned)__shfl((int)rec[1], j + 2);
            unsigned rxD = (unsigned)__shfl((int)rec[0], j + 3);
            unsigned ryD = (unsigned)__shfl((int)rec[1], j + 3);
            float xA = (float)xh[(size_t)(rxA & 0xFFFFu) * D_FEAT + lane];
            float xB = (float)xh[(size_t)(rxB & 0xFFFFu) * D_FEAT + lane];
            float xC = (float)xh[(size_t)(rxC & 0xFFFFu) * D_FEAT + lane];
            float xD = (float)xh[(size_t)(rxD & 0xFFFFu) * D_FEAT + lane];
            a0 = fmaf(h2f_bits(rxA >> 16),     xA, a0);
            a1 = fmaf(h2f_bits(ryA & 0xFFFFu), xA, a1);
            a2 = fmaf(h2f_bits(ryA >> 16),     xA, a2);
            b0 = fmaf(h2f_bits(rxB >> 16),     xB, b0);
            b1 = fmaf(h2f_bits(ryB & 0xFFFFu), xB, b1);
            b2 = fmaf(h2f_bits(ryB >> 16),     xB, b2);
            c0 = fmaf(h2f_bits(rxC >> 16),     xC, c0);
            c1 = fmaf(h2f_bits(ryC & 0xFFFFu), xC, c1);
            c2 = fmaf(h2f_bits(ryC >> 16),     xC, c2);
            d0 = fmaf(h2f_bits(rxD >> 16),     xD, d0);
            d1 = fmaf(h2f_bits(ryD & 0xFFFFu), xD, d1);
            d2 = fmaf(h2f_bits(ryD >> 16),     xD, d2);
        }
        for (; j < m; ++j) {
            unsigned rx0 = (unsigned)__shfl((int)rec[0], j);
            unsigned ry0 = (unsigned)__shfl((int)rec[1], j);
            float xa = (float)xh[(size_t)(rx0 & 0xFFFFu) * D_FEAT + lane];
            a0 = fmaf(h2f_bits(rx0 >> 16),     xa, a0);
            a1 = fmaf(h2f_bits(ry0 & 0xFFFFu), xa, a1);
            a2 = fmaf(h2f_bits(ry0 >> 16),     xa, a2);
        }
    }
    a0 += b0 + c0 + d0;
    a1 += b1 + c1 + d1;
    a2 += b2 + c2 + d2;

    float xn = __builtin_nontemporal_load(x + (size_t)n * D_FEAT + lane);
    _Float16* vr = v + (size_t)n * CD;
    __builtin_nontemporal_store((_Float16)(a0 + (1.f + eps[0]) * xn), vr + lane);
    __builtin_nontemporal_store((_Float16)(a1 + (1.f + eps[1]) * xn), vr + 64 + lane);
    __builtin_nontemporal_store((_Float16)(a2 + (1.f + eps[2]) * xn), vr + 128 + lane);
}

// --- K5: MLP1(lrelu) + MLP2 via f16 MFMA ------------------------------------
// v reads and out writes are stream-once -> non-temporal; weights stay cached.
__global__ __launch_bounds__(256) void k_mlp(
    const _Float16* __restrict__ v,
    const float* __restrict__ nw1, const float* __restrict__ nb1,
    const float* __restrict__ nw2, const float* __restrict__ nb2,
    float* __restrict__ out)
{
    __shared__ _Float16 vtile[16][CD + 8];     // stride 400B (16B mult)
    __shared__ _Float16 htile[16][OUT_F + 8];  // stride 272B (16B mult)

    const int tid  = threadIdx.x;
    const int lane = tid & 63;
    const int wid  = tid >> 6;
    const int arow = lane & 15;
    const int kg   = lane >> 4;
    const int o0   = wid * 32;

    half8 w1f[6][2], w2f[4][2];
#pragma unroll
    for (int kk = 0; kk < 6; ++kk)
#pragma unroll
        for (int nt = 0; nt < 2; ++nt) {
            half8 f;
            int colb = o0 + nt * 16 + arow;
            int kb = kk * 32 + kg * 8;
#pragma unroll
            for (int j = 0; j < 8; ++j)
                f[j] = (_Float16)nw1[(size_t)(kb + j) * OUT_F + colb];
            w1f[kk][nt] = f;
        }
#pragma unroll
    for (int kk = 0; kk < 4; ++kk)
#pragma unroll
        for (int nt = 0; nt < 2; ++nt) {
            half8 f;
            int colb = o0 + nt * 16 + arow;
            int kb = kk * 32 + kg * 8;
#pragma unroll
            for (int j = 0; j < 8; ++j)
                f[j] = (_Float16)nw2[(size_t)(kb + j) * OUT_F + colb];
            w2f[kk][nt] = f;
        }

    const float b1a = nb1[o0 + arow],      b1b = nb1[o0 + 16 + arow];
    const float b2a = nb2[o0 + arow],      b2b = nb2[o0 + 16 + arow];

    for (int t = blockIdx.x; t < NTILES; t += gridDim.x) {
        const int nb16 = t * 16;
        __syncthreads();

        for (int i = tid; i < 16 * (CD / 8); i += 256) {    // 384 chunks
            int row = i / (CD / 8), c8 = i % (CD / 8);
            *(half8*)&vtile[row][c8 * 8] = __builtin_nontemporal_load(
                (const half8*)(v + (size_t)(nb16 + row) * CD + c8 * 8));
        }
        __syncthreads();

        f32x4 acc0 = {0.f, 0.f, 0.f, 0.f}, acc1 = {0.f, 0.f, 0.f, 0.f};
#pragma unroll
        for (int kk = 0; kk < 6; ++kk) {
            half8 a = *(const half8*)&vtile[arow][kk * 32 + kg * 8];
            acc0 = __builtin_amdgcn_mfma_f32_16x16x32_f16(a, w1f[kk][0], acc0, 0, 0, 0);
            acc1 = __builtin_amdgcn_mfma_f32_16x16x32_f16(a, w1f[kk][1], acc1, 0, 0, 0);
        }
#pragma unroll
        for (int r = 0; r < 4; ++r) {
            int hr = kg * 4 + r;
            htile[hr][o0 + arow]      = (_Float16)lrelu(acc0[r] + b1a);
            htile[hr][o0 + 16 + arow] = (_Float16)lrelu(acc1[r] + b1b);
        }
        __syncthreads();

        f32x4 c0 = {0.f, 0.f, 0.f, 0.f}, c1 = {0.f, 0.f, 0.f, 0.f};
#pragma unroll
        for (int kk = 0; kk < 4; ++kk) {
            half8 a = *(const half8*)&htile[arow][kk * 32 + kg * 8];
            c0 = __builtin_amdgcn_mfma_f32_16x16x32_f16(a, w2f[kk][0], c0, 0, 0, 0);
            c1 = __builtin_amdgcn_mfma_f32_16x16x32_f16(a, w2f[kk][1], c1, 0, 0, 0);
        }
#pragma unroll
        for (int r = 0; r < 4; ++r) {
            size_t n = (size_t)(nb16 + kg * 4 + r);
            __builtin_nontemporal_store(c0[r] + b2a, &out[n * OUT_F + o0 + arow]);
            __builtin_nontemporal_store(c1[r] + b2b, &out[n * OUT_F + o0 + 16 + arow]);
        }
    }
}

extern "C" void kernel_launch(void* const* d_in, const int* in_sizes, int n_in,
                              void* d_out, int out_size, void* d_ws, size_t ws_size,
                              hipStream_t stream)
{
    const float* x    = (const float*)d_in[0];
    const int*   ei   = (const int*)  d_in[1];
    const float* ea   = (const float*)d_in[2];
    const float* w1   = (const float*)d_in[3];
    const float* b1   = (const float*)d_in[4];
    const float* w2   = (const float*)d_in[5];
    const float* b2   = (const float*)d_in[6];
    const float* eps  = (const float*)d_in[7];
    const float* nw1  = (const float*)d_in[8];
    const float* nb1  = (const float*)d_in[9];
    const float* nw2  = (const float*)d_in[10];
    const float* nb2  = (const float*)d_in[11];
    float* out = (float*)d_out;

    // workspace layout (max 34.2 MB < proven 38.4 MB)
    char* ws = (char*)d_ws;
    int*       counts    = (int*)    (ws + 0);               // 200 KB
    int*       offsets   = (int*)    (ws + (256 << 10));     // 200 KB
    int*       blocksums = (int*)    (ws + (512 << 10));     // <1 KB
    uint2*     sorted    = (uint2*)  (ws + (1u << 20));      // 6.4 MB
    _Float16*  xh        = (_Float16*)(ws + (8u << 20));     // 6.4 MB
    _Float16*  v         = (_Float16*)(ws + (15u << 20));    // 19.2 MB

    hipMemsetAsync(counts, 0, N_NODES * sizeof(int), stream);

    k_pre      <<<XCVT_BLOCKS + HIST_BLOCKS, 256, 0, stream>>>(x, xh, ei, counts);
    k_blocksum <<<NBLK_SCAN,        256, 0, stream>>>(counts, blocksums);
    k_scanfinal<<<NBLK_SCAN,        256, 0, stream>>>(counts, blocksums, offsets);
    k_place    <<<PLACE_SLICES * 8, 256, 0, stream>>>(ei, ea, w1, b1, w2, b2, offsets, sorted);
    k_gather   <<<N_NODES / 4,      256, 0, stream>>>(sorted, offsets, xh, x, eps, v);
    k_mlp      <<<768,              256, 0, stream>>>(v, nw1, nb1, nw2, nb2, out);
}

// Round 17
// 141.726 us; speedup vs baseline: 1.0898x; 1.0898x over previous
//
#include <hip/hip_runtime.h>
#include <math.h>

#define N_NODES 50000
#define E_EDGES 800000
#define D_FEAT  64
#define C_CH    3
#define H_HID   8
#define OUT_F   128
#define CD      192              // C*D
#define NTILES  (N_NODES / 16)   // 3125 exact
#define NBLK_SCAN ((N_NODES + 255) / 256)   // 196
#define PLACE_CHUNK  2048
#define PLACE_SLICES ((E_EDGES + PLACE_CHUNK - 1) / PLACE_CHUNK)  // 391
#define NPART8 (N_NODES / 8)     // 6250 exact
#define XCVT_BLOCKS (N_NODES * D_FEAT / 4 / 256)   // 3125
#define HIST_BLOCKS (E_EDGES / 256)                // 3125

typedef _Float16 half8 __attribute__((ext_vector_type(8)));
typedef _Float16 half4 __attribute__((ext_vector_type(4)));
typedef float f32x4 __attribute__((ext_vector_type(4)));

__device__ __forceinline__ float lrelu(float v) { return v >= 0.f ? v : 0.01f * v; }

__device__ __forceinline__ unsigned short f2h_bits(float f) {
    _Float16 h = (_Float16)f;
    unsigned short b;
    __builtin_memcpy(&b, &h, 2);
    return b;
}
__device__ __forceinline__ float h2f_bits(unsigned b) {
    unsigned short s = (unsigned short)b;
    _Float16 h;
    __builtin_memcpy(&h, &s, 2);
    return (float)h;
}

// --- K1: fused {x f32->f16 convert} + {dst histogram} -----------------------
__global__ __launch_bounds__(256) void k_pre(
    const float* __restrict__ x, _Float16* __restrict__ xh,
    const int* __restrict__ ei, int* __restrict__ counts)
{
    if (blockIdx.x < XCVT_BLOCKS) {
        int i = blockIdx.x * 256 + threadIdx.x;
        float4 f = ((const float4*)x)[i];
        half4 h;
        h[0] = (_Float16)f.x; h[1] = (_Float16)f.y;
        h[2] = (_Float16)f.z; h[3] = (_Float16)f.w;
        *(half4*)(xh + (size_t)i * 4) = h;
        return;
    }
    int e = (blockIdx.x - XCVT_BLOCKS) * 256 + threadIdx.x;
    atomicAdd(counts + ei[E_EDGES + e], 1);   // no return use
}

// --- K2a: per-block sums of counts ------------------------------------------
__global__ __launch_bounds__(256) void k_blocksum(
    const int* __restrict__ counts, int* __restrict__ blocksums)
{
    __shared__ int s[256];
    int i = blockIdx.x * 256 + threadIdx.x;
    s[threadIdx.x] = (i < N_NODES) ? counts[i] : 0;
    __syncthreads();
    for (int off = 128; off >= 1; off >>= 1) {
        if (threadIdx.x < off) s[threadIdx.x] += s[threadIdx.x + off];
        __syncthreads();
    }
    if (threadIdx.x == 0) blocksums[blockIdx.x] = s[0];
}

// --- K2b: fused {scan of blocksums (redundant per block)} + final scan ------
__global__ __launch_bounds__(256) void k_scanfinal(
    const int* __restrict__ counts, const int* __restrict__ blocksums,
    int* __restrict__ offsets)
{
    __shared__ int bs[256];
    __shared__ int s[256];
    const int tid = threadIdx.x;

    bs[tid] = (tid < NBLK_SCAN) ? blocksums[tid] : 0;
    __syncthreads();
    for (int off = 1; off < 256; off <<= 1) {
        int t = (tid >= off) ? bs[tid - off] : 0;
        __syncthreads();
        bs[tid] += t;
        __syncthreads();
    }
    const int blockoff = (blockIdx.x == 0) ? 0 : bs[blockIdx.x - 1];

    int i = blockIdx.x * 256 + tid;
    int v = (i < N_NODES) ? counts[i] : 0;
    s[tid] = v;
    __syncthreads();
    for (int off = 1; off < 256; off <<= 1) {
        int t = (tid >= off) ? s[tid - off] : 0;
        __syncthreads();
        s[tid] += t;
        __syncthreads();
    }
    if (i < N_NODES) offsets[i] = s[tid] - v + blockoff;   // exclusive
}

// --- K3: XCD-partitioned edge-MLP + record scatter, COMPACTED ---------------
// group g = blockIdx&7 owns dst range [g*6250,(g+1)*6250): cursors + record
// region stay in ONE XCD's L2. Phase A ballot-compacts in-range edges of the
// 2048-chunk into LDS; phase B runs the edge MLP lane-DENSE and scatters.
__global__ __launch_bounds__(256) void k_place(
    const int* __restrict__ ei, const float* __restrict__ ea,
    const float* __restrict__ w1, const float* __restrict__ b1,
    const float* __restrict__ w2, const float* __restrict__ b2,
    int* __restrict__ offsets, uint2* __restrict__ sorted)
{
    __shared__ int   s_src[PLACE_CHUNK];
    __shared__ float s_ea [PLACE_CHUNK];
    __shared__ int   s_dd [PLACE_CHUNK];
    __shared__ int   lcnt;

    const int tid   = threadIdx.x;
    const int lane  = tid & 63;
    const int g     = blockIdx.x & 7;
    const int slice = blockIdx.x >> 3;
    const int lo    = g * NPART8;
    const int hi    = lo + NPART8;
    const int e0    = slice * PLACE_CHUNK + tid * 8;
    const int* dstp = ei + E_EDGES;

    if (tid == 0) lcnt = 0;
    __syncthreads();

    int   se[8];
    int   de[8];
    float aev[8];
    if (e0 + 7 < E_EDGES) {
        int4   sv0 = *(const int4*)(ei + e0);
        int4   sv1 = *(const int4*)(ei + e0 + 4);
        int4   d0  = *(const int4*)(dstp + e0);
        int4   d1  = *(const int4*)(dstp + e0 + 4);
        float4 a0  = *(const float4*)(ea + e0);
        float4 a1  = *(const float4*)(ea + e0 + 4);
        se[0]=sv0.x; se[1]=sv0.y; se[2]=sv0.z; se[3]=sv0.w;
        se[4]=sv1.x; se[5]=sv1.y; se[6]=sv1.z; se[7]=sv1.w;
        de[0]=d0.x;  de[1]=d0.y;  de[2]=d0.z;  de[3]=d0.w;
        de[4]=d1.x;  de[5]=d1.y;  de[6]=d1.z;  de[7]=d1.w;
        aev[0]=a0.x; aev[1]=a0.y; aev[2]=a0.z; aev[3]=a0.w;
        aev[4]=a1.x; aev[5]=a1.y; aev[6]=a1.z; aev[7]=a1.w;
    } else {
#pragma unroll
        for (int j = 0; j < 8; ++j) {
            int e = e0 + j;
            se[j]  = (e < E_EDGES) ? ei[e]   : 0;
            de[j]  = (e < E_EDGES) ? dstp[e] : -1;
            aev[j] = (e < E_EDGES) ? ea[e]   : 0.f;
        }
    }

    // phase A: wave-ballot compaction into LDS
#pragma unroll
    for (int j = 0; j < 8; ++j) {
        bool p = (de[j] >= lo && de[j] < hi);
        unsigned long long mask = __ballot(p);
        int total = __popcll(mask);
        int wbase = 0;
        if (lane == 0 && total) wbase = atomicAdd(&lcnt, total);
        wbase = __shfl(wbase, 0);
        if (p) {
            int pos = wbase + __popcll(mask & ((1ull << lane) - 1ull));
            s_src[pos] = se[j];
            s_ea [pos] = aev[j];
            s_dd [pos] = de[j];
        }
    }
    __syncthreads();

    // phase B: dense edge MLP + scatter
    const int cnt = lcnt;
    for (int i = tid; i < cnt; i += 256) {
        float a = s_ea[i];
        float wc[C_CH];
#pragma unroll
        for (int c = 0; c < C_CH; ++c) {
            float s = 0.f;
#pragma unroll
            for (int h = 0; h < H_HID; ++h) {
                float t = fmaf(a, w1[c * H_HID + h], b1[c * H_HID + h]);
                t = (t >= 0.f) ? t : 0.01f * t;               // leaky_relu
                s = fmaf(t, w2[c * H_HID + h], s);
            }
            s += b2[c];
            wc[c] = (s > 0.f) ? s : expm1f(s);                // elu
        }
        uint2 r;
        r.x = (unsigned)s_src[i] | ((unsigned)f2h_bits(wc[0]) << 16);
        r.y = (unsigned)f2h_bits(wc[1]) | ((unsigned)f2h_bits(wc[2]) << 16);
        sorted[atomicAdd(offsets + s_dd[i], 1)] = r;
    }
}

// --- K4: gather (f16 x rows) + residual -> v[N][192] f16 --------------------
// one wave per node; lanes batch-fetch 64 records COALESCED, then 8-wide
// shfl-broadcast inner loop: 8 independent 128B x-row gathers in flight.
__global__ __launch_bounds__(256) void k_gather(
    const uint2* __restrict__ sorted, const int* __restrict__ endoff,
    const _Float16* __restrict__ xh, const float* __restrict__ x,
    const float* __restrict__ eps, _Float16* __restrict__ v)
{
    const int n    = blockIdx.x * 4 + (threadIdx.x >> 6);   // grid = N/4 exact
    const int lane = threadIdx.x & 63;

    const int start = (n == 0) ? 0 : endoff[n - 1];
    const int end   = endoff[n];

    float a0 = 0.f, a1 = 0.f, a2 = 0.f;
    float b0 = 0.f, b1 = 0.f, b2 = 0.f;
    float c0 = 0.f, c1 = 0.f, c2 = 0.f;
    float d0 = 0.f, d1 = 0.f, d2 = 0.f;

    for (int base = start; base < end; base += 64) {
        const int m = min(64, end - base);
        uint2 rec = make_uint2(0u, 0u);
        if (lane < m) rec = sorted[base + lane];     // coalesced 8B
        int j = 0;
        for (; j + 8 <= m; j += 8) {
            unsigned rxA = (unsigned)__shfl((int)rec.x, j);
            unsigned ryA = (unsigned)__shfl((int)rec.y, j);
            unsigned rxB = (unsigned)__shfl((int)rec.x, j + 1);
            unsigned ryB = (unsigned)__shfl((int)rec.y, j + 1);
            unsigned rxC = (unsigned)__shfl((int)rec.x, j + 2);
            unsigned ryC = (unsigned)__shfl((int)rec.y, j + 2);
            unsigned rxD = (unsigned)__shfl((int)rec.x, j + 3);
            unsigned ryD = (unsigned)__shfl((int)rec.y, j + 3);
            unsigned rxE = (unsigned)__shfl((int)rec.x, j + 4);
            unsigned ryE = (unsigned)__shfl((int)rec.y, j + 4);
            unsigned rxF = (unsigned)__shfl((int)rec.x, j + 5);
            unsigned ryF = (unsigned)__shfl((int)rec.y, j + 5);
            unsigned rxG = (unsigned)__shfl((int)rec.x, j + 6);
            unsigned ryG = (unsigned)__shfl((int)rec.y, j + 6);
            unsigned rxH = (unsigned)__shfl((int)rec.x, j + 7);
            unsigned ryH = (unsigned)__shfl((int)rec.y, j + 7);
            float xA = (float)xh[(size_t)(rxA & 0xFFFFu) * D_FEAT + lane];
            float xB = (float)xh[(size_t)(rxB & 0xFFFFu) * D_FEAT + lane];
            float xC = (float)xh[(size_t)(rxC & 0xFFFFu) * D_FEAT + lane];
            float xD = (float)xh[(size_t)(rxD & 0xFFFFu) * D_FEAT + lane];
            float xE = (float)xh[(size_t)(rxE & 0xFFFFu) * D_FEAT + lane];
            float xF = (float)xh[(size_t)(rxF & 0xFFFFu) * D_FEAT + lane];
            float xG = (float)xh[(size_t)(rxG & 0xFFFFu) * D_FEAT + lane];
            float xH = (float)xh[(size_t)(rxH & 0xFFFFu) * D_FEAT + lane];
            a0 = fmaf(h2f_bits(rxA >> 16),     xA, a0);
            a1 = fmaf(h2f_bits(ryA & 0xFFFFu), xA, a1);
            a2 = fmaf(h2f_bits(ryA >> 16),     xA, a2);
            b0 = fmaf(h2f_bits(rxB >> 16),     xB, b0);
            b1 = fmaf(h2f_bits(ryB & 0xFFFFu), xB, b1);
            b2 = fmaf(h2f_bits(ryB >> 16),     xB, b2);
            c0 = fmaf(h2f_bits(rxC >> 16),     xC, c0);
            c1 = fmaf(h2f_bits(ryC & 0xFFFFu), xC, c1);
            c2 = fmaf(h2f_bits(ryC >> 16),     xC, c2);
            d0 = fmaf(h2f_bits(rxD >> 16),     xD, d0);
            d1 = fmaf(h2f_bits(ryD & 0xFFFFu), xD, d1);
            d2 = fmaf(h2f_bits(ryD >> 16),     xD, d2);
            a0 = fmaf(h2f_bits(rxE >> 16),     xE, a0);
            a1 = fmaf(h2f_bits(ryE & 0xFFFFu), xE, a1);
            a2 = fmaf(h2f_bits(ryE >> 16),     xE, a2);
            b0 = fmaf(h2f_bits(rxF >> 16),     xF, b0);
            b1 = fmaf(h2f_bits(ryF & 0xFFFFu), xF, b1);
            b2 = fmaf(h2f_bits(ryF >> 16),     xF, b2);
            c0 = fmaf(h2f_bits(rxG >> 16),     xG, c0);
            c1 = fmaf(h2f_bits(ryG & 0xFFFFu), xG, c1);
            c2 = fmaf(h2f_bits(ryG >> 16),     xG, c2);
            d0 = fmaf(h2f_bits(rxH >> 16),     xH, d0);
            d1 = fmaf(h2f_bits(ryH & 0xFFFFu), xH, d1);
            d2 = fmaf(h2f_bits(ryH >> 16),     xH, d2);
        }
        for (; j < m; ++j) {
            unsigned rx0 = (unsigned)__shfl((int)rec.x, j);
            unsigned ry0 = (unsigned)__shfl((int)rec.y, j);
            float xa = (float)xh[(size_t)(rx0 & 0xFFFFu) * D_FEAT + lane];
            a0 = fmaf(h2f_bits(rx0 >> 16),     xa, a0);
            a1 = fmaf(h2f_bits(ry0 & 0xFFFFu), xa, a1);
            a2 = fmaf(h2f_bits(ry0 >> 16),     xa, a2);
        }
    }
    a0 += b0 + c0 + d0;
    a1 += b1 + c1 + d1;
    a2 += b2 + c2 + d2;

    float xn = x[(size_t)n * D_FEAT + lane];
    _Float16* vr = v + (size_t)n * CD;
    vr[lane]       = (_Float16)(a0 + (1.f + eps[0]) * xn);
    vr[64 + lane]  = (_Float16)(a1 + (1.f + eps[1]) * xn);
    vr[128 + lane] = (_Float16)(a2 + (1.f + eps[2]) * xn);
}

// --- K5: MLP1(lrelu) + MLP2 via f16 MFMA ------------------------------------
__global__ __launch_bounds__(256) void k_mlp(
    const _Float16* __restrict__ v,
    const float* __restrict__ nw1, const float* __restrict__ nb1,
    const float* __restrict__ nw2, const float* __restrict__ nb2,
    float* __restrict__ out)
{
    __shared__ _Float16 vtile[16][CD + 8];     // stride 400B (16B mult)
    __shared__ _Float16 htile[16][OUT_F + 8];  // stride 272B (16B mult)

    const int tid  = threadIdx.x;
    const int lane = tid & 63;
    const int wid  = tid >> 6;
    const int arow = lane & 15;
    const int kg   = lane >> 4;
    const int o0   = wid * 32;

    half8 w1f[6][2], w2f[4][2];
#pragma unroll
    for (int kk = 0; kk < 6; ++kk)
#pragma unroll
        for (int nt = 0; nt < 2; ++nt) {
            half8 f;
            int colb = o0 + nt * 16 + arow;
            int kb = kk * 32 + kg * 8;
#pragma unroll
            for (int j = 0; j < 8; ++j)
                f[j] = (_Float16)nw1[(size_t)(kb + j) * OUT_F + colb];
            w1f[kk][nt] = f;
        }
#pragma unroll
    for (int kk = 0; kk < 4; ++kk)
#pragma unroll
        for (int nt = 0; nt < 2; ++nt) {
            half8 f;
            int colb = o0 + nt * 16 + arow;
            int kb = kk * 32 + kg * 8;
#pragma unroll
            for (int j = 0; j < 8; ++j)
                f[j] = (_Float16)nw2[(size_t)(kb + j) * OUT_F + colb];
            w2f[kk][nt] = f;
        }

    const float b1a = nb1[o0 + arow],      b1b = nb1[o0 + 16 + arow];
    const float b2a = nb2[o0 + arow],      b2b = nb2[o0 + 16 + arow];

    for (int t = blockIdx.x; t < NTILES; t += gridDim.x) {
        const int nb16 = t * 16;
        __syncthreads();

        for (int i = tid; i < 16 * (CD / 8); i += 256) {    // 384 chunks
            int row = i / (CD / 8), c8 = i % (CD / 8);
            *(half8*)&vtile[row][c8 * 8] =
                *(const half8*)(v + (size_t)(nb16 + row) * CD + c8 * 8);
        }
        __syncthreads();

        f32x4 acc0 = {0.f, 0.f, 0.f, 0.f}, acc1 = {0.f, 0.f, 0.f, 0.f};
#pragma unroll
        for (int kk = 0; kk < 6; ++kk) {
            half8 a = *(const half8*)&vtile[arow][kk * 32 + kg * 8];
            acc0 = __builtin_amdgcn_mfma_f32_16x16x32_f16(a, w1f[kk][0], acc0, 0, 0, 0);
            acc1 = __builtin_amdgcn_mfma_f32_16x16x32_f16(a, w1f[kk][1], acc1, 0, 0, 0);
        }
#pragma unroll
        for (int r = 0; r < 4; ++r) {
            int hr = kg * 4 + r;
            htile[hr][o0 + arow]      = (_Float16)lrelu(acc0[r] + b1a);
            htile[hr][o0 + 16 + arow] = (_Float16)lrelu(acc1[r] + b1b);
        }
        __syncthreads();

        f32x4 c0 = {0.f, 0.f, 0.f, 0.f}, c1 = {0.f, 0.f, 0.f, 0.f};
#pragma unroll
        for (int kk = 0; kk < 4; ++kk) {
            half8 a = *(const half8*)&htile[arow][kk * 32 + kg * 8];
            c0 = __builtin_amdgcn_mfma_f32_16x16x32_f16(a, w2f[kk][0], c0, 0, 0, 0);
            c1 = __builtin_amdgcn_mfma_f32_16x16x32_f16(a, w2f[kk][1], c1, 0, 0, 0);
        }
#pragma unroll
        for (int r = 0; r < 4; ++r) {
            size_t n = (size_t)(nb16 + kg * 4 + r);
            out[n * OUT_F + o0 + arow]      = c0[r] + b2a;
            out[n * OUT_F + o0 + 16 + arow] = c1[r] + b2b;
        }
    }
}

extern "C" void kernel_launch(void* const* d_in, const int* in_sizes, int n_in,
                              void* d_out, int out_size, void* d_ws, size_t ws_size,
                              hipStream_t stream)
{
    const float* x    = (const float*)d_in[0];
    const int*   ei   = (const int*)  d_in[1];
    const float* ea   = (const float*)d_in[2];
    const float* w1   = (const float*)d_in[3];
    const float* b1   = (const float*)d_in[4];
    const float* w2   = (const float*)d_in[5];
    const float* b2   = (const float*)d_in[6];
    const float* eps  = (const float*)d_in[7];
    const float* nw1  = (const float*)d_in[8];
    const float* nb1  = (const float*)d_in[9];
    const float* nw2  = (const float*)d_in[10];
    const float* nb2  = (const float*)d_in[11];
    float* out = (float*)d_out;

    // workspace layout (max 34.2 MB < proven 38.4 MB)
    char* ws = (char*)d_ws;
    int*       counts    = (int*)    (ws + 0);               // 200 KB
    int*       offsets   = (int*)    (ws + (256 << 10));     // 200 KB
    int*       blocksums = (int*)    (ws + (512 << 10));     // <1 KB
    uint2*     sorted    = (uint2*)  (ws + (1u << 20));      // 6.4 MB
    _Float16*  xh        = (_Float16*)(ws + (8u << 20));     // 6.4 MB
    _Float16*  v         = (_Float16*)(ws + (15u << 20));    // 19.2 MB

    hipMemsetAsync(counts, 0, N_NODES * sizeof(int), stream);

    k_pre      <<<XCVT_BLOCKS + HIST_BLOCKS, 256, 0, stream>>>(x, xh, ei, counts);
    k_blocksum <<<NBLK_SCAN,        256, 0, stream>>>(counts, blocksums);
    k_scanfinal<<<NBLK_SCAN,        256, 0, stream>>>(counts, blocksums, offsets);
    k_place    <<<PLACE_SLICES * 8, 256, 0, stream>>>(ei, ea, w1, b1, w2, b2, offsets, sorted);
    k_gather   <<<N_NODES / 4,      256, 0, stream>>>(sorted, offsets, xh, x, eps, v);
    k_mlp      <<<768,              256, 0, stream>>>(v, nw1, nb1, nw2, nb2, out);
}

// Round 18
// 135.622 us; speedup vs baseline: 1.1389x; 1.0450x over previous
//
#include <hip/hip_runtime.h>
#include <math.h>

#define N_NODES 50000
#define E_EDGES 800000
#define D_FEAT  64
#define C_CH    3
#define H_HID   8
#define OUT_F   128
#define CD      192              // C*D
#define NTILES  (N_NODES / 16)   // 3125 exact
#define NBLK_SCAN ((N_NODES + 255) / 256)   // 196
#define XCVT_BLOCKS (N_NODES * D_FEAT / 4 / 256)   // 3125
#define EDGE_BLOCKS (E_EDGES / 256)                // 3125

typedef _Float16 half8 __attribute__((ext_vector_type(8)));
typedef _Float16 half4 __attribute__((ext_vector_type(4)));
typedef float f32x4 __attribute__((ext_vector_type(4)));

__device__ __forceinline__ float lrelu(float v) { return v >= 0.f ? v : 0.01f * v; }

__device__ __forceinline__ unsigned short f2h_bits(float f) {
    _Float16 h = (_Float16)f;
    unsigned short b;
    __builtin_memcpy(&b, &h, 2);
    return b;
}
__device__ __forceinline__ float h2f_bits(unsigned b) {
    unsigned short s = (unsigned short)b;
    _Float16 h;
    __builtin_memcpy(&h, &s, 2);
    return (float)h;
}

// --- K1: fused {x f32->f16} + {edge MLP -> wbuf + rank = hist return} -------
// rank[e] = this edge's arrival index among same-dst edges. All stores
// coalesced; the only random op is the histogram atomic (now with return).
__global__ __launch_bounds__(256) void k_pre(
    const float* __restrict__ x, _Float16* __restrict__ xh,
    const int* __restrict__ ei, const float* __restrict__ ea,
    const float* __restrict__ w1, const float* __restrict__ b1,
    const float* __restrict__ w2, const float* __restrict__ b2,
    uint2* __restrict__ wbuf, int* __restrict__ rank,
    int* __restrict__ counts)
{
    if (blockIdx.x < XCVT_BLOCKS) {
        int i = blockIdx.x * 256 + threadIdx.x;
        float4 f = ((const float4*)x)[i];
        half4 h;
        h[0] = (_Float16)f.x; h[1] = (_Float16)f.y;
        h[2] = (_Float16)f.z; h[3] = (_Float16)f.w;
        *(half4*)(xh + (size_t)i * 4) = h;
        return;
    }
    int e = (blockIdx.x - XCVT_BLOCKS) * 256 + threadIdx.x;
    int src = ei[e];
    int dst = ei[E_EDGES + e];
    float a = ea[e];
    float wc[C_CH];
#pragma unroll
    for (int c = 0; c < C_CH; ++c) {
        float s = 0.f;
#pragma unroll
        for (int h = 0; h < H_HID; ++h) {
            float t = fmaf(a, w1[c * H_HID + h], b1[c * H_HID + h]);
            t = (t >= 0.f) ? t : 0.01f * t;               // leaky_relu
            s = fmaf(t, w2[c * H_HID + h], s);
        }
        s += b2[c];
        wc[c] = (s > 0.f) ? s : expm1f(s);                // elu
    }
    uint2 r;
    r.x = (unsigned)src | ((unsigned)f2h_bits(wc[0]) << 16);
    r.y = (unsigned)f2h_bits(wc[1]) | ((unsigned)f2h_bits(wc[2]) << 16);
    wbuf[e] = r;
    rank[e] = atomicAdd(counts + dst, 1);   // hist + rank in one atomic
}

// --- K2a: per-block sums of counts ------------------------------------------
__global__ __launch_bounds__(256) void k_blocksum(
    const int* __restrict__ counts, int* __restrict__ blocksums)
{
    __shared__ int s[256];
    int i = blockIdx.x * 256 + threadIdx.x;
    s[threadIdx.x] = (i < N_NODES) ? counts[i] : 0;
    __syncthreads();
    for (int off = 128; off >= 1; off >>= 1) {
        if (threadIdx.x < off) s[threadIdx.x] += s[threadIdx.x + off];
        __syncthreads();
    }
    if (threadIdx.x == 0) blocksums[blockIdx.x] = s[0];
}

// --- K2b: fused {scan of blocksums (redundant per block)} + final scan ------
__global__ __launch_bounds__(256) void k_scanfinal(
    const int* __restrict__ counts, const int* __restrict__ blocksums,
    int* __restrict__ offsets)
{
    __shared__ int bs[256];
    __shared__ int s[256];
    const int tid = threadIdx.x;

    bs[tid] = (tid < NBLK_SCAN) ? blocksums[tid] : 0;
    __syncthreads();
    for (int off = 1; off < 256; off <<= 1) {
        int t = (tid >= off) ? bs[tid - off] : 0;
        __syncthreads();
        bs[tid] += t;
        __syncthreads();
    }
    const int blockoff = (blockIdx.x == 0) ? 0 : bs[blockIdx.x - 1];

    int i = blockIdx.x * 256 + tid;
    int v = (i < N_NODES) ? counts[i] : 0;
    s[tid] = v;
    __syncthreads();
    for (int off = 1; off < 256; off <<= 1) {
        int t = (tid >= off) ? s[tid - off] : 0;
        __syncthreads();
        s[tid] += t;
        __syncthreads();
    }
    if (i < N_NODES) offsets[i] = s[tid] - v + blockoff;   // exclusive
}

// --- K3: rank-based scatter — NO atomics, NO redundancy, 1 edge/thread ------
// pos = offsets[dst] + rank  is fully determined; pure fire-and-forget.
__global__ __launch_bounds__(256) void k_scat(
    const int* __restrict__ ei, const int* __restrict__ rank,
    const uint2* __restrict__ wbuf, const int* __restrict__ offsets,
    uint2* __restrict__ sorted)
{
    int e = blockIdx.x * 256 + threadIdx.x;    // grid covers E exactly
    int d = ei[E_EDGES + e];
    int pos = offsets[d] + rank[e];            // offsets random 4B, L2-hot
    sorted[pos] = wbuf[e];                     // 8B scatter, no dependency
}

// --- K4: gather (f16 x rows) + residual -> v[N][192] f16 --------------------
// one wave per node; lanes batch-fetch 64 records COALESCED, then 4-wide
// shfl-broadcast inner loop with independent 128B x-row gathers.
__global__ __launch_bounds__(256) void k_gather(
    const uint2* __restrict__ sorted, const int* __restrict__ offsets,
    const _Float16* __restrict__ xh, const float* __restrict__ x,
    const float* __restrict__ eps, _Float16* __restrict__ v)
{
    const int n    = blockIdx.x * 4 + (threadIdx.x >> 6);   // grid = N/4 exact
    const int lane = threadIdx.x & 63;

    const int start = offsets[n];
    const int end   = (n + 1 < N_NODES) ? offsets[n + 1] : E_EDGES;

    float a0 = 0.f, a1 = 0.f, a2 = 0.f;
    float b0 = 0.f, b1 = 0.f, b2 = 0.f;
    float c0 = 0.f, c1 = 0.f, c2 = 0.f;
    float d0 = 0.f, d1 = 0.f, d2 = 0.f;

    for (int base = start; base < end; base += 64) {
        const int m = min(64, end - base);
        uint2 rec = make_uint2(0u, 0u);
        if (lane < m) rec = sorted[base + lane];     // coalesced 8B
        int j = 0;
        for (; j + 4 <= m; j += 4) {
            unsigned rxA = (unsigned)__shfl((int)rec.x, j);
            unsigned ryA = (unsigned)__shfl((int)rec.y, j);
            unsigned rxB = (unsigned)__shfl((int)rec.x, j + 1);
            unsigned ryB = (unsigned)__shfl((int)rec.y, j + 1);
            unsigned rxC = (unsigned)__shfl((int)rec.x, j + 2);
            unsigned ryC = (unsigned)__shfl((int)rec.y, j + 2);
            unsigned rxD = (unsigned)__shfl((int)rec.x, j + 3);
            unsigned ryD = (unsigned)__shfl((int)rec.y, j + 3);
            float xA = (float)xh[(size_t)(rxA & 0xFFFFu) * D_FEAT + lane];
            float xB = (float)xh[(size_t)(rxB & 0xFFFFu) * D_FEAT + lane];
            float xC = (float)xh[(size_t)(rxC & 0xFFFFu) * D_FEAT + lane];
            float xD = (float)xh[(size_t)(rxD & 0xFFFFu) * D_FEAT + lane];
            a0 = fmaf(h2f_bits(rxA >> 16),     xA, a0);
            a1 = fmaf(h2f_bits(ryA & 0xFFFFu), xA, a1);
            a2 = fmaf(h2f_bits(ryA >> 16),     xA, a2);
            b0 = fmaf(h2f_bits(rxB >> 16),     xB, b0);
            b1 = fmaf(h2f_bits(ryB & 0xFFFFu), xB, b1);
            b2 = fmaf(h2f_bits(ryB >> 16),     xB, b2);
            c0 = fmaf(h2f_bits(rxC >> 16),     xC, c0);
            c1 = fmaf(h2f_bits(ryC & 0xFFFFu), xC, c1);
            c2 = fmaf(h2f_bits(ryC >> 16),     xC, c2);
            d0 = fmaf(h2f_bits(rxD >> 16),     xD, d0);
            d1 = fmaf(h2f_bits(ryD & 0xFFFFu), xD, d1);
            d2 = fmaf(h2f_bits(ryD >> 16),     xD, d2);
        }
        for (; j < m; ++j) {
            unsigned rx0 = (unsigned)__shfl((int)rec.x, j);
            unsigned ry0 = (unsigned)__shfl((int)rec.y, j);
            float xa = (float)xh[(size_t)(rx0 & 0xFFFFu) * D_FEAT + lane];
            a0 = fmaf(h2f_bits(rx0 >> 16),     xa, a0);
            a1 = fmaf(h2f_bits(ry0 & 0xFFFFu), xa, a1);
            a2 = fmaf(h2f_bits(ry0 >> 16),     xa, a2);
        }
    }
    a0 += b0 + c0 + d0;
    a1 += b1 + c1 + d1;
    a2 += b2 + c2 + d2;

    float xn = x[(size_t)n * D_FEAT + lane];
    _Float16* vr = v + (size_t)n * CD;
    vr[lane]       = (_Float16)(a0 + (1.f + eps[0]) * xn);
    vr[64 + lane]  = (_Float16)(a1 + (1.f + eps[1]) * xn);
    vr[128 + lane] = (_Float16)(a2 + (1.f + eps[2]) * xn);
}

// --- K5: MLP1(lrelu) + MLP2 via f16 MFMA ------------------------------------
__global__ __launch_bounds__(256) void k_mlp(
    const _Float16* __restrict__ v,
    const float* __restrict__ nw1, const float* __restrict__ nb1,
    const float* __restrict__ nw2, const float* __restrict__ nb2,
    float* __restrict__ out)
{
    __shared__ _Float16 vtile[16][CD + 8];     // stride 400B (16B mult)
    __shared__ _Float16 htile[16][OUT_F + 8];  // stride 272B (16B mult)

    const int tid  = threadIdx.x;
    const int lane = tid & 63;
    const int wid  = tid >> 6;
    const int arow = lane & 15;
    const int kg   = lane >> 4;
    const int o0   = wid * 32;

    half8 w1f[6][2], w2f[4][2];
#pragma unroll
    for (int kk = 0; kk < 6; ++kk)
#pragma unroll
        for (int nt = 0; nt < 2; ++nt) {
            half8 f;
            int colb = o0 + nt * 16 + arow;
            int kb = kk * 32 + kg * 8;
#pragma unroll
            for (int j = 0; j < 8; ++j)
                f[j] = (_Float16)nw1[(size_t)(kb + j) * OUT_F + colb];
            w1f[kk][nt] = f;
        }
#pragma unroll
    for (int kk = 0; kk < 4; ++kk)
#pragma unroll
        for (int nt = 0; nt < 2; ++nt) {
            half8 f;
            int colb = o0 + nt * 16 + arow;
            int kb = kk * 32 + kg * 8;
#pragma unroll
            for (int j = 0; j < 8; ++j)
                f[j] = (_Float16)nw2[(size_t)(kb + j) * OUT_F + colb];
            w2f[kk][nt] = f;
        }

    const float b1a = nb1[o0 + arow],      b1b = nb1[o0 + 16 + arow];
    const float b2a = nb2[o0 + arow],      b2b = nb2[o0 + 16 + arow];

    for (int t = blockIdx.x; t < NTILES; t += gridDim.x) {
        const int nb16 = t * 16;
        __syncthreads();

        for (int i = tid; i < 16 * (CD / 8); i += 256) {    // 384 chunks
            int row = i / (CD / 8), c8 = i % (CD / 8);
            *(half8*)&vtile[row][c8 * 8] =
                *(const half8*)(v + (size_t)(nb16 + row) * CD + c8 * 8);
        }
        __syncthreads();

        f32x4 acc0 = {0.f, 0.f, 0.f, 0.f}, acc1 = {0.f, 0.f, 0.f, 0.f};
#pragma unroll
        for (int kk = 0; kk < 6; ++kk) {
            half8 a = *(const half8*)&vtile[arow][kk * 32 + kg * 8];
            acc0 = __builtin_amdgcn_mfma_f32_16x16x32_f16(a, w1f[kk][0], acc0, 0, 0, 0);
            acc1 = __builtin_amdgcn_mfma_f32_16x16x32_f16(a, w1f[kk][1], acc1, 0, 0, 0);
        }
#pragma unroll
        for (int r = 0; r < 4; ++r) {
            int hr = kg * 4 + r;
            htile[hr][o0 + arow]      = (_Float16)lrelu(acc0[r] + b1a);
            htile[hr][o0 + 16 + arow] = (_Float16)lrelu(acc1[r] + b1b);
        }
        __syncthreads();

        f32x4 c0 = {0.f, 0.f, 0.f, 0.f}, c1 = {0.f, 0.f, 0.f, 0.f};
#pragma unroll
        for (int kk = 0; kk < 4; ++kk) {
            half8 a = *(const half8*)&htile[arow][kk * 32 + kg * 8];
            c0 = __builtin_amdgcn_mfma_f32_16x16x32_f16(a, w2f[kk][0], c0, 0, 0, 0);
            c1 = __builtin_amdgcn_mfma_f32_16x16x32_f16(a, w2f[kk][1], c1, 0, 0, 0);
        }
#pragma unroll
        for (int r = 0; r < 4; ++r) {
            size_t n = (size_t)(nb16 + kg * 4 + r);
            out[n * OUT_F + o0 + arow]      = c0[r] + b2a;
            out[n * OUT_F + o0 + 16 + arow] = c1[r] + b2b;
        }
    }
}

extern "C" void kernel_launch(void* const* d_in, const int* in_sizes, int n_in,
                              void* d_out, int out_size, void* d_ws, size_t ws_size,
                              hipStream_t stream)
{
    const float* x    = (const float*)d_in[0];
    const int*   ei   = (const int*)  d_in[1];
    const float* ea   = (const float*)d_in[2];
    const float* w1   = (const float*)d_in[3];
    const float* b1   = (const float*)d_in[4];
    const float* w2   = (const float*)d_in[5];
    const float* b2   = (const float*)d_in[6];
    const float* eps  = (const float*)d_in[7];
    const float* nw1  = (const float*)d_in[8];
    const float* nb1  = (const float*)d_in[9];
    const float* nw2  = (const float*)d_in[10];
    const float* nb2  = (const float*)d_in[11];
    float* out = (float*)d_out;

    // ws layout: 0.5 + 3.2 + 6.4 + 6.4 + 19.2 = ~36.2 MB (38.4 proven)
    char* ws = (char*)d_ws;
    int*       counts    = (int*)    (ws + 0);               // 200 KB
    int*       offsets   = (int*)    (ws + (256 << 10));     // 200 KB
    int*       blocksums = (int*)    (ws + (512 << 10));     // <1 KB
    int*       rank      = (int*)    (ws + (1u << 20));      // 3.2 MB
    uint2*     wbuf      = (uint2*)  (ws + (1u << 20) + 3276800);           // 6.4 MB
    uint2*     sorted    = (uint2*)  (ws + (1u << 20) + 3276800 + 6400000); // 6.4 MB
    _Float16*  v         = (_Float16*)(ws + (1u << 20) + 3276800 + 12800000); // 19.2 MB

    // xh lives in d_out (6.4 MB of 25.6 MB); dead before k_mlp overwrites
    // (proven safe in round 14)
    _Float16* xh = (_Float16*)d_out;

    hipMemsetAsync(counts, 0, N_NODES * sizeof(int), stream);

    k_pre      <<<XCVT_BLOCKS + EDGE_BLOCKS, 256, 0, stream>>>(
        x, xh, ei, ea, w1, b1, w2, b2, wbuf, rank, counts);
    k_blocksum <<<NBLK_SCAN,   256, 0, stream>>>(counts, blocksums);
    k_scanfinal<<<NBLK_SCAN,   256, 0, stream>>>(counts, blocksums, offsets);
    k_scat     <<<EDGE_BLOCKS, 256, 0, stream>>>(ei, rank, wbuf, offsets, sorted);
    k_gather   <<<N_NODES / 4, 256, 0, stream>>>(sorted, offsets, xh, x, eps, v);
    k_mlp      <<<768,         256, 0, stream>>>(v, nw1, nb1, nw2, nb2, out);
}

// Round 19
// 111.169 us; speedup vs baseline: 1.3894x; 1.2200x over previous
//
#include <hip/hip_runtime.h>
#include <math.h>

#define N_NODES 50000
#define E_EDGES 800000
#define D_FEAT  64
#define C_CH    3
#define H_HID   8
#define OUT_F   128
#define CD      192              // C*D
#define NTILES  (N_NODES / 16)   // 3125 exact
#define NBLK_SCAN ((N_NODES + 255) / 256)   // 196
#define XCVT_BLOCKS (N_NODES * D_FEAT / 4 / 256)   // 3125
#define EDGE_BLOCKS (E_EDGES / 256)                // 3125
#define NREP 8

typedef _Float16 half8 __attribute__((ext_vector_type(8)));
typedef _Float16 half4 __attribute__((ext_vector_type(4)));
typedef float f32x4 __attribute__((ext_vector_type(4)));

__device__ __forceinline__ float lrelu(float v) { return v >= 0.f ? v : 0.01f * v; }

__device__ __forceinline__ unsigned short f2h_bits(float f) {
    _Float16 h = (_Float16)f;
    unsigned short b;
    __builtin_memcpy(&b, &h, 2);
    return b;
}
__device__ __forceinline__ float h2f_bits(unsigned b) {
    unsigned short s = (unsigned short)b;
    _Float16 h;
    __builtin_memcpy(&h, &s, 2);
    return (float)h;
}

// --- K1: fused {x f32->f16} + {edge MLP -> wbuf + XCD-local rank} -----------
// Each block's XCD group g = blockIdx&7 owns count replica counts8[g][*]
// (200 KB, L2-resident, single-XCD traffic -> fast atomics). rank[e] is the
// within-replica arrival index (u16). All other stores coalesced.
__global__ __launch_bounds__(256) void k_pre(
    const float* __restrict__ x, _Float16* __restrict__ xh,
    const int* __restrict__ ei, const float* __restrict__ ea,
    const float* __restrict__ w1, const float* __restrict__ b1,
    const float* __restrict__ w2, const float* __restrict__ b2,
    uint2* __restrict__ wbuf, unsigned short* __restrict__ rank,
    int* __restrict__ counts8)
{
    if (blockIdx.x < XCVT_BLOCKS) {
        int i = blockIdx.x * 256 + threadIdx.x;
        float4 f = ((const float4*)x)[i];
        half4 h;
        h[0] = (_Float16)f.x; h[1] = (_Float16)f.y;
        h[2] = (_Float16)f.z; h[3] = (_Float16)f.w;
        *(half4*)(xh + (size_t)i * 4) = h;
        return;
    }
    const int g = blockIdx.x & 7;                 // round-robin XCD id
    int e = (blockIdx.x - XCVT_BLOCKS) * 256 + threadIdx.x;
    int src = ei[e];
    int dst = ei[E_EDGES + e];
    float a = ea[e];
    float wc[C_CH];
#pragma unroll
    for (int c = 0; c < C_CH; ++c) {
        float s = 0.f;
#pragma unroll
        for (int h = 0; h < H_HID; ++h) {
            float t = fmaf(a, w1[c * H_HID + h], b1[c * H_HID + h]);
            t = (t >= 0.f) ? t : 0.01f * t;               // leaky_relu
            s = fmaf(t, w2[c * H_HID + h], s);
        }
        s += b2[c];
        wc[c] = (s > 0.f) ? s : expm1f(s);                // elu
    }
    uint2 r;
    r.x = (unsigned)src | ((unsigned)f2h_bits(wc[0]) << 16);
    r.y = (unsigned)f2h_bits(wc[1]) | ((unsigned)f2h_bits(wc[2]) << 16);
    wbuf[e] = r;
    rank[e] = (unsigned short)atomicAdd(counts8 + g * N_NODES + dst, 1);
}

// --- K2a: per-block sums of total counts (sum over 8 replicas) --------------
__global__ __launch_bounds__(256) void k_blocksum(
    const int* __restrict__ counts8, int* __restrict__ blocksums)
{
    __shared__ int s[256];
    int i = blockIdx.x * 256 + threadIdx.x;
    int t = 0;
    if (i < N_NODES)
#pragma unroll
        for (int g = 0; g < NREP; ++g) t += counts8[g * N_NODES + i];
    s[threadIdx.x] = t;
    __syncthreads();
    for (int off = 128; off >= 1; off >>= 1) {
        if (threadIdx.x < off) s[threadIdx.x] += s[threadIdx.x + off];
        __syncthreads();
    }
    if (threadIdx.x == 0) blocksums[blockIdx.x] = s[0];
}

// --- K2b: scan -> offsets[n] + per-replica bases repl_base[g][n] ------------
__global__ __launch_bounds__(256) void k_scanfinal(
    const int* __restrict__ counts8, const int* __restrict__ blocksums,
    int* __restrict__ offsets, int* __restrict__ repl_base)
{
    __shared__ int bs[256];
    __shared__ int s[256];
    const int tid = threadIdx.x;

    bs[tid] = (tid < NBLK_SCAN) ? blocksums[tid] : 0;
    __syncthreads();
    for (int off = 1; off < 256; off <<= 1) {
        int t = (tid >= off) ? bs[tid - off] : 0;
        __syncthreads();
        bs[tid] += t;
        __syncthreads();
    }
    const int blockoff = (blockIdx.x == 0) ? 0 : bs[blockIdx.x - 1];

    int i = blockIdx.x * 256 + tid;
    int cg[NREP];
    int v = 0;
    if (i < N_NODES) {
#pragma unroll
        for (int g = 0; g < NREP; ++g) {
            cg[g] = counts8[g * N_NODES + i];
            v += cg[g];
        }
    }
    s[tid] = v;
    __syncthreads();
    for (int off = 1; off < 256; off <<= 1) {
        int t = (tid >= off) ? s[tid - off] : 0;
        __syncthreads();
        s[tid] += t;
        __syncthreads();
    }
    if (i < N_NODES) {
        int excl = s[tid] - v + blockoff;      // exclusive global offset
        offsets[i] = excl;
        int run = excl;
#pragma unroll
        for (int g = 0; g < NREP; ++g) {
            repl_base[g * N_NODES + i] = run;
            run += cg[g];
        }
    }
}

// --- K3: rank-based scatter — NO atomics, 1 edge/thread ---------------------
// pos = repl_base[g(e)][dst] + rank[e], fully determined. g(e) reconstructs
// the XCD group of the k_pre block that processed edge e.
__global__ __launch_bounds__(256) void k_scat(
    const int* __restrict__ ei, const unsigned short* __restrict__ rank,
    const uint2* __restrict__ wbuf, const int* __restrict__ repl_base,
    uint2* __restrict__ sorted)
{
    int e = blockIdx.x * 256 + threadIdx.x;    // grid covers E exactly
    int d = ei[E_EDGES + e];
    int g = (XCVT_BLOCKS + (e >> 8)) & 7;      // k_pre's blockIdx & 7
    int pos = repl_base[g * N_NODES + d] + (int)rank[e];
    sorted[pos] = wbuf[e];                     // 8B scatter, no dependency
}

// --- K4: gather (f16 x rows) + residual -> v[N][192] f16 --------------------
__global__ __launch_bounds__(256) void k_gather(
    const uint2* __restrict__ sorted, const int* __restrict__ offsets,
    const _Float16* __restrict__ xh, const float* __restrict__ x,
    const float* __restrict__ eps, _Float16* __restrict__ v)
{
    const int n    = blockIdx.x * 4 + (threadIdx.x >> 6);   // grid = N/4 exact
    const int lane = threadIdx.x & 63;

    const int start = offsets[n];
    const int end   = (n + 1 < N_NODES) ? offsets[n + 1] : E_EDGES;

    float a0 = 0.f, a1 = 0.f, a2 = 0.f;
    float b0 = 0.f, b1 = 0.f, b2 = 0.f;
    float c0 = 0.f, c1 = 0.f, c2 = 0.f;
    float d0 = 0.f, d1 = 0.f, d2 = 0.f;

    for (int base = start; base < end; base += 64) {
        const int m = min(64, end - base);
        uint2 rec = make_uint2(0u, 0u);
        if (lane < m) rec = sorted[base + lane];     // coalesced 8B
        int j = 0;
        for (; j + 4 <= m; j += 4) {
            unsigned rxA = (unsigned)__shfl((int)rec.x, j);
            unsigned ryA = (unsigned)__shfl((int)rec.y, j);
            unsigned rxB = (unsigned)__shfl((int)rec.x, j + 1);
            unsigned ryB = (unsigned)__shfl((int)rec.y, j + 1);
            unsigned rxC = (unsigned)__shfl((int)rec.x, j + 2);
            unsigned ryC = (unsigned)__shfl((int)rec.y, j + 2);
            unsigned rxD = (unsigned)__shfl((int)rec.x, j + 3);
            unsigned ryD = (unsigned)__shfl((int)rec.y, j + 3);
            float xA = (float)xh[(size_t)(rxA & 0xFFFFu) * D_FEAT + lane];
            float xB = (float)xh[(size_t)(rxB & 0xFFFFu) * D_FEAT + lane];
            float xC = (float)xh[(size_t)(rxC & 0xFFFFu) * D_FEAT + lane];
            float xD = (float)xh[(size_t)(rxD & 0xFFFFu) * D_FEAT + lane];
            a0 = fmaf(h2f_bits(rxA >> 16),     xA, a0);
            a1 = fmaf(h2f_bits(ryA & 0xFFFFu), xA, a1);
            a2 = fmaf(h2f_bits(ryA >> 16),     xA, a2);
            b0 = fmaf(h2f_bits(rxB >> 16),     xB, b0);
            b1 = fmaf(h2f_bits(ryB & 0xFFFFu), xB, b1);
            b2 = fmaf(h2f_bits(ryB >> 16),     xB, b2);
            c0 = fmaf(h2f_bits(rxC >> 16),     xC, c0);
            c1 = fmaf(h2f_bits(ryC & 0xFFFFu), xC, c1);
            c2 = fmaf(h2f_bits(ryC >> 16),     xC, c2);
            d0 = fmaf(h2f_bits(rxD >> 16),     xD, d0);
            d1 = fmaf(h2f_bits(ryD & 0xFFFFu), xD, d1);
            d2 = fmaf(h2f_bits(ryD >> 16),     xD, d2);
        }
        for (; j < m; ++j) {
            unsigned rx0 = (unsigned)__shfl((int)rec.x, j);
            unsigned ry0 = (unsigned)__shfl((int)rec.y, j);
            float xa = (float)xh[(size_t)(rx0 & 0xFFFFu) * D_FEAT + lane];
            a0 = fmaf(h2f_bits(rx0 >> 16),     xa, a0);
            a1 = fmaf(h2f_bits(ry0 & 0xFFFFu), xa, a1);
            a2 = fmaf(h2f_bits(ry0 >> 16),     xa, a2);
        }
    }
    a0 += b0 + c0 + d0;
    a1 += b1 + c1 + d1;
    a2 += b2 + c2 + d2;

    float xn = x[(size_t)n * D_FEAT + lane];
    _Float16* vr = v + (size_t)n * CD;
    vr[lane]       = (_Float16)(a0 + (1.f + eps[0]) * xn);
    vr[64 + lane]  = (_Float16)(a1 + (1.f + eps[1]) * xn);
    vr[128 + lane] = (_Float16)(a2 + (1.f + eps[2]) * xn);
}

// --- K5: MLP1(lrelu) + MLP2 via f16 MFMA ------------------------------------
__global__ __launch_bounds__(256) void k_mlp(
    const _Float16* __restrict__ v,
    const float* __restrict__ nw1, const float* __restrict__ nb1,
    const float* __restrict__ nw2, const float* __restrict__ nb2,
    float* __restrict__ out)
{
    __shared__ _Float16 vtile[16][CD + 8];     // stride 400B (16B mult)
    __shared__ _Float16 htile[16][OUT_F + 8];  // stride 272B (16B mult)

    const int tid  = threadIdx.x;
    const int lane = tid & 63;
    const int wid  = tid >> 6;
    const int arow = lane & 15;
    const int kg   = lane >> 4;
    const int o0   = wid * 32;

    half8 w1f[6][2], w2f[4][2];
#pragma unroll
    for (int kk = 0; kk < 6; ++kk)
#pragma unroll
        for (int nt = 0; nt < 2; ++nt) {
            half8 f;
            int colb = o0 + nt * 16 + arow;
            int kb = kk * 32 + kg * 8;
#pragma unroll
            for (int j = 0; j < 8; ++j)
                f[j] = (_Float16)nw1[(size_t)(kb + j) * OUT_F + colb];
            w1f[kk][nt] = f;
        }
#pragma unroll
    for (int kk = 0; kk < 4; ++kk)
#pragma unroll
        for (int nt = 0; nt < 2; ++nt) {
            half8 f;
            int colb = o0 + nt * 16 + arow;
            int kb = kk * 32 + kg * 8;
#pragma unroll
            for (int j = 0; j < 8; ++j)
                f[j] = (_Float16)nw2[(size_t)(kb + j) * OUT_F + colb];
            w2f[kk][nt] = f;
        }

    const float b1a = nb1[o0 + arow],      b1b = nb1[o0 + 16 + arow];
    const float b2a = nb2[o0 + arow],      b2b = nb2[o0 + 16 + arow];

    for (int t = blockIdx.x; t < NTILES; t += gridDim.x) {
        const int nb16 = t * 16;
        __syncthreads();

        for (int i = tid; i < 16 * (CD / 8); i += 256) {    // 384 chunks
            int row = i / (CD / 8), c8 = i % (CD / 8);
            *(half8*)&vtile[row][c8 * 8] =
                *(const half8*)(v + (size_t)(nb16 + row) * CD + c8 * 8);
        }
        __syncthreads();

        f32x4 acc0 = {0.f, 0.f, 0.f, 0.f}, acc1 = {0.f, 0.f, 0.f, 0.f};
#pragma unroll
        for (int kk = 0; kk < 6; ++kk) {
            half8 a = *(const half8*)&vtile[arow][kk * 32 + kg * 8];
            acc0 = __builtin_amdgcn_mfma_f32_16x16x32_f16(a, w1f[kk][0], acc0, 0, 0, 0);
            acc1 = __builtin_amdgcn_mfma_f32_16x16x32_f16(a, w1f[kk][1], acc1, 0, 0, 0);
        }
#pragma unroll
        for (int r = 0; r < 4; ++r) {
            int hr = kg * 4 + r;
            htile[hr][o0 + arow]      = (_Float16)lrelu(acc0[r] + b1a);
            htile[hr][o0 + 16 + arow] = (_Float16)lrelu(acc1[r] + b1b);
        }
        __syncthreads();

        f32x4 c0 = {0.f, 0.f, 0.f, 0.f}, c1 = {0.f, 0.f, 0.f, 0.f};
#pragma unroll
        for (int kk = 0; kk < 4; ++kk) {
            half8 a = *(const half8*)&htile[arow][kk * 32 + kg * 8];
            c0 = __builtin_amdgcn_mfma_f32_16x16x32_f16(a, w2f[kk][0], c0, 0, 0, 0);
            c1 = __builtin_amdgcn_mfma_f32_16x16x32_f16(a, w2f[kk][1], c1, 0, 0, 0);
        }
#pragma unroll
        for (int r = 0; r < 4; ++r) {
            size_t n = (size_t)(nb16 + kg * 4 + r);
            out[n * OUT_F + o0 + arow]      = c0[r] + b2a;
            out[n * OUT_F + o0 + 16 + arow] = c1[r] + b2b;
        }
    }
}

extern "C" void kernel_launch(void* const* d_in, const int* in_sizes, int n_in,
                              void* d_out, int out_size, void* d_ws, size_t ws_size,
                              hipStream_t stream)
{
    const float* x    = (const float*)d_in[0];
    const int*   ei   = (const int*)  d_in[1];
    const float* ea   = (const float*)d_in[2];
    const float* w1   = (const float*)d_in[3];
    const float* b1   = (const float*)d_in[4];
    const float* w2   = (const float*)d_in[5];
    const float* b2   = (const float*)d_in[6];
    const float* eps  = (const float*)d_in[7];
    const float* nw1  = (const float*)d_in[8];
    const float* nb1  = (const float*)d_in[9];
    const float* nw2  = (const float*)d_in[10];
    const float* nb2  = (const float*)d_in[11];
    float* out = (float*)d_out;

    // ws layout (bytes): total ~37.0 MB <= proven 38.4 MB
    char* ws = (char*)d_ws;
    int*            counts8   = (int*)           (ws + 0);          // 1,600,000
    int*            blocksums = (int*)           (ws + 1600000);    // 784
    int*            offsets   = (int*)           (ws + 1604096);    // 200,000
    int*            repl_base = (int*)           (ws + 1804800);    // 1,600,000
    unsigned short* rank      = (unsigned short*)(ws + 3404800);    // 1,600,000
    uint2*          wbuf      = (uint2*)         (ws + 5004800);    // 6,400,000
    uint2*          sorted    = (uint2*)         (ws + 11404800);   // 6,400,000
    _Float16*       v         = (_Float16*)      (ws + 17804800);   // 19,200,000

    // xh lives in d_out (6.4 MB of 25.6 MB); dead before k_mlp overwrites
    // (proven safe in round 14/18)
    _Float16* xh = (_Float16*)d_out;

    hipMemsetAsync(counts8, 0, NREP * N_NODES * sizeof(int), stream);

    k_pre      <<<XCVT_BLOCKS + EDGE_BLOCKS, 256, 0, stream>>>(
        x, xh, ei, ea, w1, b1, w2, b2, wbuf, rank, counts8);
    k_blocksum <<<NBLK_SCAN,   256, 0, stream>>>(counts8, blocksums);
    k_scanfinal<<<NBLK_SCAN,   256, 0, stream>>>(counts8, blocksums, offsets, repl_base);
    k_scat     <<<EDGE_BLOCKS, 256, 0, stream>>>(ei, rank, wbuf, repl_base, sorted);
    k_gather   <<<N_NODES / 4, 256, 0, stream>>>(sorted, offsets, xh, x, eps, v);
    k_mlp      <<<768,         256, 0, stream>>>(v, nw1, nb1, nw2, nb2, out);
}